// Round 1
// baseline (8607.240 us; speedup 1.0000x reference)
//
#include <hip/hip_runtime.h>
#include <hip/hip_bf16.h>

#define N_NODES 100000
#define N_EDGES 3200000
#define DIM 64
#define OUT_COLS 256

// ---------------------------------------------------------------------------
// init: h = x ; out[:, 0:64] = x
// ---------------------------------------------------------------------------
__global__ void init_kernel(const float* __restrict__ x,
                            float* __restrict__ h,
                            float* __restrict__ out) {
    int i = blockIdx.x * blockDim.x + threadIdx.x;   // float4 index
    const int total = N_NODES * DIM / 4;
    if (i < total) {
        float4 v = ((const float4*)x)[i];
        ((float4*)h)[i] = v;
        int elem = i * 4;
        int node = elem >> 6;        // /64
        int c    = elem & 63;
        *(float4*)&out[node * OUT_COLS + c] = v;
    }
}

// ---------------------------------------------------------------------------
// scatter: h_n[dst[e]] += a[e] * h[src[e]]   (16 threads per edge, float4 each)
// ---------------------------------------------------------------------------
__global__ void scatter_kernel(const float* __restrict__ h,
                               const float* __restrict__ a,
                               const int* __restrict__ src,
                               const int* __restrict__ dst,
                               float* __restrict__ hn) {
    int gid = blockIdx.x * blockDim.x + threadIdx.x;
    int e = gid >> 4;           // edge
    int q = gid & 15;           // float4 chunk within the 64-dim row
    if (e < N_EDGES) {
        int s = src[e];
        int d = dst[e];
        float ae = a[e];
        float4 v = *(const float4*)&h[s * DIM + q * 4];
        float* p = &hn[d * DIM + q * 4];
        atomicAdd(p + 0, v.x * ae);
        atomicAdd(p + 1, v.y * ae);
        atomicAdd(p + 2, v.z * ae);
        atomicAdd(p + 3, v.w * ae);
    }
}

// ---------------------------------------------------------------------------
// update: t1 = h + h_n ; t2 = h * h_n
//         h <- leaky(t1 @ W1 + b1) + leaky(t2 @ W2 + b2) ; also write to out
// Block = 256 threads = 4 waves; each wave (slot) handles one node at a time.
// Thread caches its W1/W2 output-column in registers (64+64 fp32).
// ---------------------------------------------------------------------------
__global__ __launch_bounds__(256) void update_kernel(
        float* __restrict__ h,
        const float* __restrict__ hn,
        const float* __restrict__ W1,
        const float* __restrict__ b1,
        const float* __restrict__ W2,
        const float* __restrict__ b2,
        float* __restrict__ out,
        int out_col_base) {
    __shared__ float s_t1[4][DIM];
    __shared__ float s_t2[4][DIM];

    const int col  = threadIdx.x & 63;
    const int slot = threadIdx.x >> 6;

    // W columns into registers (coalesced: consecutive lanes read consecutive cols)
    float w1c[DIM], w2c[DIM];
#pragma unroll
    for (int k = 0; k < DIM; ++k) {
        w1c[k] = W1[k * DIM + col];
        w2c[k] = W2[k * DIM + col];
    }
    const float bb1 = b1[col];
    const float bb2 = b2[col];

    for (int base = blockIdx.x * 4; base < N_NODES; base += gridDim.x * 4) {
        const int node = base + slot;
        const bool valid = (node < N_NODES);
        float hv = 0.f, hnv = 0.f;
        if (valid) {
            hv  = h[node * DIM + col];
            hnv = hn[node * DIM + col];
        }
        s_t1[slot][col] = hv + hnv;
        s_t2[slot][col] = hv * hnv;
        __syncthreads();

        float acc1 = bb1, acc2 = bb2;
        const float4* t1v = (const float4*)s_t1[slot];
        const float4* t2v = (const float4*)s_t2[slot];
#pragma unroll
        for (int k0 = 0; k0 < DIM / 4; ++k0) {
            float4 t1 = t1v[k0];   // LDS broadcast (same addr across wave)
            float4 t2 = t2v[k0];
            acc1 = fmaf(t1.x, w1c[4 * k0 + 0], acc1);
            acc1 = fmaf(t1.y, w1c[4 * k0 + 1], acc1);
            acc1 = fmaf(t1.z, w1c[4 * k0 + 2], acc1);
            acc1 = fmaf(t1.w, w1c[4 * k0 + 3], acc1);
            acc2 = fmaf(t2.x, w2c[4 * k0 + 0], acc2);
            acc2 = fmaf(t2.y, w2c[4 * k0 + 1], acc2);
            acc2 = fmaf(t2.z, w2c[4 * k0 + 2], acc2);
            acc2 = fmaf(t2.w, w2c[4 * k0 + 3], acc2);
        }
        __syncthreads();   // protect s_t1/s_t2 before next iteration overwrites

        if (valid) {
            float r1 = acc1 > 0.f ? acc1 : 0.01f * acc1;
            float r2 = acc2 > 0.f ? acc2 : 0.01f * acc2;
            float hnew = r1 + r2;
            h[node * DIM + col] = hnew;
            out[node * OUT_COLS + out_col_base + col] = hnew;
        }
    }
}

// ---------------------------------------------------------------------------
extern "C" void kernel_launch(void* const* d_in, const int* in_sizes, int n_in,
                              void* d_out, int out_size, void* d_ws, size_t ws_size,
                              hipStream_t stream) {
    const float* x   = (const float*)d_in[0];
    const float* a   = (const float*)d_in[1];
    const float* W1s = (const float*)d_in[2];
    const float* b1s = (const float*)d_in[3];
    const float* W2s = (const float*)d_in[4];
    const float* b2s = (const float*)d_in[5];
    const int*   src = (const int*)d_in[6];
    const int*   dst = (const int*)d_in[7];
    float* out = (float*)d_out;

    float* h  = (float*)d_ws;                       // [N, 64]
    float* hn = h + (size_t)N_NODES * DIM;          // [N, 64]

    // h = x ; out[:, :64] = x
    {
        int total = N_NODES * DIM / 4;
        init_kernel<<<(total + 255) / 256, 256, 0, stream>>>(x, h, out);
    }

    for (int l = 0; l < 3; ++l) {
        hipMemsetAsync(hn, 0, (size_t)N_NODES * DIM * sizeof(float), stream);
        {
            int total = N_EDGES * 16;
            scatter_kernel<<<(total + 255) / 256, 256, 0, stream>>>(h, a, src, dst, hn);
        }
        update_kernel<<<1024, 256, 0, stream>>>(
            h, hn,
            W1s + (size_t)l * DIM * DIM, b1s + (size_t)l * DIM,
            W2s + (size_t)l * DIM * DIM, b2s + (size_t)l * DIM,
            out, (l + 1) * DIM);
    }
}

// Round 2
// 1682.349 us; speedup vs baseline: 5.1162x; 5.1162x over previous
//
#include <hip/hip_runtime.h>
#include <hip/hip_bf16.h>

#define N_NODES 100000
#define N_EDGES 3200000
#define DIM 64
#define OUT_COLS 256
#define SCAN_THREADS 1024
#define CHUNK 98   // ceil(N_NODES / SCAN_THREADS)

// ---------------------------------------------------------------------------
// init: h = x ; out[:, 0:64] = x
// ---------------------------------------------------------------------------
__global__ void init_kernel(const float* __restrict__ x,
                            float* __restrict__ h,
                            float* __restrict__ out) {
    int i = blockIdx.x * blockDim.x + threadIdx.x;   // float4 index
    const int total = N_NODES * DIM / 4;
    if (i < total) {
        float4 v = ((const float4*)x)[i];
        ((float4*)h)[i] = v;
        int elem = i * 4;
        int node = elem >> 6;
        int c    = elem & 63;
        *(float4*)&out[node * OUT_COLS + c] = v;
    }
}

// ---------------------------------------------------------------------------
// CSR build step 1: histogram of dst
// ---------------------------------------------------------------------------
__global__ void hist_kernel(const int* __restrict__ dst, int* __restrict__ counts) {
    int e = blockIdx.x * blockDim.x + threadIdx.x;
    if (e < N_EDGES) atomicAdd(&counts[dst[e]], 1);
}

// ---------------------------------------------------------------------------
// CSR build step 2: single-block exclusive scan (counts -> offsets, cursor)
// ---------------------------------------------------------------------------
__global__ __launch_bounds__(SCAN_THREADS) void scan_kernel(
        const int* __restrict__ counts,
        int* __restrict__ offsets,      // [N+1]
        int* __restrict__ cursor) {     // [N]
    __shared__ int s[SCAN_THREADS];
    const int t = threadIdx.x;
    const int base = t * CHUNK;

    int sum = 0;
    for (int i = 0; i < CHUNK; ++i) {
        int idx = base + i;
        if (idx < N_NODES) sum += counts[idx];
    }
    s[t] = sum;
    __syncthreads();
    // Hillis-Steele inclusive scan over 1024 partials
    for (int off = 1; off < SCAN_THREADS; off <<= 1) {
        int v = 0;
        if (t >= off) v = s[t - off];
        __syncthreads();
        if (t >= off) s[t] += v;
        __syncthreads();
    }
    int run = (t == 0) ? 0 : s[t - 1];   // exclusive base for this chunk
    for (int i = 0; i < CHUNK; ++i) {
        int idx = base + i;
        if (idx < N_NODES) {
            offsets[idx] = run;
            cursor[idx]  = run;
            run += counts[idx];
        }
    }
    if (t == SCAN_THREADS - 1) offsets[N_NODES] = run;
}

// ---------------------------------------------------------------------------
// CSR build step 3: fill edge records (src, a) bucketed by dst
// ---------------------------------------------------------------------------
__global__ void fill_kernel(const int* __restrict__ src,
                            const int* __restrict__ dst,
                            const float* __restrict__ a,
                            int* __restrict__ cursor,
                            int2* __restrict__ edges) {
    int e = blockIdx.x * blockDim.x + threadIdx.x;
    if (e < N_EDGES) {
        int pos = atomicAdd(&cursor[dst[e]], 1);
        edges[pos] = make_int2(src[e], __float_as_int(a[e]));
    }
}

// ---------------------------------------------------------------------------
// gather: hn[v][lane] = sum over edges (u->v) of a_e * h[u][lane]
// One wave (64 lanes) per node; lane = feature column. No atomics.
// ---------------------------------------------------------------------------
__global__ __launch_bounds__(256) void gather_kernel(
        const float* __restrict__ h,
        const int2* __restrict__ edges,
        const int* __restrict__ offsets,
        float* __restrict__ hn) {
    const int lane = threadIdx.x & 63;
    const int node = (blockIdx.x * blockDim.x + threadIdx.x) >> 6;
    if (node >= N_NODES) return;

    const int beg = offsets[node];
    const int end = offsets[node + 1];
    float acc = 0.f;

    for (int i = beg; i < end; i += 64) {
        const int cnt = min(64, end - i);
        int2 ed = make_int2(0, 0);
        if (lane < cnt) ed = edges[i + lane];
        for (int j = 0; j < cnt; ++j) {
            int   sj = __shfl(ed.x, j);
            float aj = __int_as_float(__shfl(ed.y, j));
            acc = fmaf(aj, h[(size_t)sj * DIM + lane], acc);
        }
    }
    hn[(size_t)node * DIM + lane] = acc;
}

// ---------------------------------------------------------------------------
// update: t1 = h + h_n ; t2 = h * h_n
//         h <- leaky(t1 @ W1 + b1) + leaky(t2 @ W2 + b2) ; also write to out
// ---------------------------------------------------------------------------
__global__ __launch_bounds__(256) void update_kernel(
        float* __restrict__ h,
        const float* __restrict__ hn,
        const float* __restrict__ W1,
        const float* __restrict__ b1,
        const float* __restrict__ W2,
        const float* __restrict__ b2,
        float* __restrict__ out,
        int out_col_base) {
    __shared__ float s_t1[4][DIM];
    __shared__ float s_t2[4][DIM];

    const int col  = threadIdx.x & 63;
    const int slot = threadIdx.x >> 6;

    float w1c[DIM], w2c[DIM];
#pragma unroll
    for (int k = 0; k < DIM; ++k) {
        w1c[k] = W1[k * DIM + col];
        w2c[k] = W2[k * DIM + col];
    }
    const float bb1 = b1[col];
    const float bb2 = b2[col];

    for (int base = blockIdx.x * 4; base < N_NODES; base += gridDim.x * 4) {
        const int node = base + slot;
        const bool valid = (node < N_NODES);
        float hv = 0.f, hnv = 0.f;
        if (valid) {
            hv  = h[node * DIM + col];
            hnv = hn[node * DIM + col];
        }
        s_t1[slot][col] = hv + hnv;
        s_t2[slot][col] = hv * hnv;
        __syncthreads();

        float acc1 = bb1, acc2 = bb2;
        const float4* t1v = (const float4*)s_t1[slot];
        const float4* t2v = (const float4*)s_t2[slot];
#pragma unroll
        for (int k0 = 0; k0 < DIM / 4; ++k0) {
            float4 t1 = t1v[k0];
            float4 t2 = t2v[k0];
            acc1 = fmaf(t1.x, w1c[4 * k0 + 0], acc1);
            acc1 = fmaf(t1.y, w1c[4 * k0 + 1], acc1);
            acc1 = fmaf(t1.z, w1c[4 * k0 + 2], acc1);
            acc1 = fmaf(t1.w, w1c[4 * k0 + 3], acc1);
            acc2 = fmaf(t2.x, w2c[4 * k0 + 0], acc2);
            acc2 = fmaf(t2.y, w2c[4 * k0 + 1], acc2);
            acc2 = fmaf(t2.z, w2c[4 * k0 + 2], acc2);
            acc2 = fmaf(t2.w, w2c[4 * k0 + 3], acc2);
        }
        __syncthreads();

        if (valid) {
            float r1 = acc1 > 0.f ? acc1 : 0.01f * acc1;
            float r2 = acc2 > 0.f ? acc2 : 0.01f * acc2;
            float hnew = r1 + r2;
            h[node * DIM + col] = hnew;
            out[node * OUT_COLS + out_col_base + col] = hnew;
        }
    }
}

// ---------------------------------------------------------------------------
extern "C" void kernel_launch(void* const* d_in, const int* in_sizes, int n_in,
                              void* d_out, int out_size, void* d_ws, size_t ws_size,
                              hipStream_t stream) {
    const float* x   = (const float*)d_in[0];
    const float* a   = (const float*)d_in[1];
    const float* W1s = (const float*)d_in[2];
    const float* b1s = (const float*)d_in[3];
    const float* W2s = (const float*)d_in[4];
    const float* b2s = (const float*)d_in[5];
    const int*   src = (const int*)d_in[6];
    const int*   dst = (const int*)d_in[7];
    float* out = (float*)d_out;

    // workspace layout
    float* h  = (float*)d_ws;                          // [N, 64]
    float* hn = h + (size_t)N_NODES * DIM;             // [N, 64]
    int* counts  = (int*)(hn + (size_t)N_NODES * DIM); // [N]
    int* offsets = counts + N_NODES;                   // [N+1]
    int* cursor  = offsets + N_NODES + 1;              // [N]
    uintptr_t p = (uintptr_t)(cursor + N_NODES);
    p = (p + 15) & ~(uintptr_t)15;
    int2* edges = (int2*)p;                            // [E]

    // h = x ; out[:, :64] = x
    {
        int total = N_NODES * DIM / 4;
        init_kernel<<<(total + 255) / 256, 256, 0, stream>>>(x, h, out);
    }

    // build CSR (dst-bucketed edge list), once per launch
    hipMemsetAsync(counts, 0, N_NODES * sizeof(int), stream);
    hist_kernel<<<(N_EDGES + 255) / 256, 256, 0, stream>>>(dst, counts);
    scan_kernel<<<1, SCAN_THREADS, 0, stream>>>(counts, offsets, cursor);
    fill_kernel<<<(N_EDGES + 255) / 256, 256, 0, stream>>>(src, dst, a, cursor, edges);

    for (int l = 0; l < 3; ++l) {
        gather_kernel<<<(N_NODES * 64 + 255) / 256, 256, 0, stream>>>(h, edges, offsets, hn);
        update_kernel<<<1024, 256, 0, stream>>>(
            h, hn,
            W1s + (size_t)l * DIM * DIM, b1s + (size_t)l * DIM,
            W2s + (size_t)l * DIM * DIM, b2s + (size_t)l * DIM,
            out, (l + 1) * DIM);
    }
}

// Round 3
// 1205.300 us; speedup vs baseline: 7.1412x; 1.3958x over previous
//
#include <hip/hip_runtime.h>
#include <hip/hip_bf16.h>

#define N_NODES 100000
#define N_EDGES 3200000
#define DIM 64
#define OUT_COLS 256
#define ELEMS_PER_BLOCK 1024
#define NBLK ((N_NODES + ELEMS_PER_BLOCK - 1) / ELEMS_PER_BLOCK)   // 98

// ---------------------------------------------------------------------------
// init: h = x ; out[:, 0:64] = x
// ---------------------------------------------------------------------------
__global__ void init_kernel(const float* __restrict__ x,
                            float* __restrict__ h,
                            float* __restrict__ out) {
    int i = blockIdx.x * blockDim.x + threadIdx.x;   // float4 index
    const int total = N_NODES * DIM / 4;
    if (i < total) {
        float4 v = ((const float4*)x)[i];
        ((float4*)h)[i] = v;
        int elem = i * 4;
        int node = elem >> 6;
        int c    = elem & 63;
        *(float4*)&out[node * OUT_COLS + c] = v;
    }
}

// ---------------------------------------------------------------------------
// CSR build step 1: histogram of dst (4 edges / thread)
// ---------------------------------------------------------------------------
__global__ void hist_kernel(const int* __restrict__ dst, int* __restrict__ counts) {
    int t = blockIdx.x * blockDim.x + threadIdx.x;
    int e = t * 4;
    if (e + 4 <= N_EDGES) {
        int4 d = *(const int4*)&dst[e];
        atomicAdd(&counts[d.x], 1);
        atomicAdd(&counts[d.y], 1);
        atomicAdd(&counts[d.z], 1);
        atomicAdd(&counts[d.w], 1);
    } else {
        for (int k = e; k < N_EDGES; ++k) atomicAdd(&counts[dst[k]], 1);
    }
}

// ---------------------------------------------------------------------------
// scan A: per-block sums of counts (1024 elems / block)
// ---------------------------------------------------------------------------
__global__ __launch_bounds__(256) void blocksum_kernel(const int* __restrict__ counts,
                                                       int* __restrict__ bsum) {
    const int t = threadIdx.x;
    const int base = blockIdx.x * ELEMS_PER_BLOCK + t * 4;
    int s = 0;
#pragma unroll
    for (int k = 0; k < 4; ++k) {
        int idx = base + k;
        if (idx < N_NODES) s += counts[idx];
    }
    for (int off = 32; off > 0; off >>= 1) s += __shfl_down(s, off);
    __shared__ int ws[4];
    const int lane = t & 63, wv = t >> 6;
    if (lane == 0) ws[wv] = s;
    __syncthreads();
    if (t == 0) bsum[blockIdx.x] = ws[0] + ws[1] + ws[2] + ws[3];
}

// ---------------------------------------------------------------------------
// scan B: exclusive-scan the 98 block sums (single small block)
// ---------------------------------------------------------------------------
__global__ __launch_bounds__(128) void scanbsum_kernel(int* __restrict__ bsum,
                                                       int* __restrict__ offsets) {
    __shared__ int s[128];
    const int t = threadIdx.x;
    int v = (t < NBLK) ? bsum[t] : 0;
    s[t] = v;
    __syncthreads();
    for (int off = 1; off < 128; off <<= 1) {
        int u = (t >= off) ? s[t - off] : 0;
        __syncthreads();
        s[t] += u;
        __syncthreads();
    }
    if (t < NBLK) bsum[t] = s[t] - v;          // exclusive
    if (t == 127) offsets[N_NODES] = s[127];   // total edge count
}

// ---------------------------------------------------------------------------
// scan C: block-local exclusive scan + write offsets & cursor
// ---------------------------------------------------------------------------
__global__ __launch_bounds__(256) void blockscan_kernel(const int* __restrict__ counts,
                                                        const int* __restrict__ bsum,
                                                        int* __restrict__ offsets,
                                                        int* __restrict__ cursor) {
    const int t = threadIdx.x;
    const int base = blockIdx.x * ELEMS_PER_BLOCK + t * 4;
    int a = 0, b = 0, c = 0, d = 0;
    if (base + 0 < N_NODES) a = counts[base + 0];
    if (base + 1 < N_NODES) b = counts[base + 1];
    if (base + 2 < N_NODES) c = counts[base + 2];
    if (base + 3 < N_NODES) d = counts[base + 3];
    const int s = a + b + c + d;

    int incl = s;
    const int lane = t & 63, wv = t >> 6;
    for (int off = 1; off < 64; off <<= 1) {
        int u = __shfl_up(incl, off);
        if (lane >= off) incl += u;
    }
    __shared__ int ws[4];
    if (lane == 63) ws[wv] = incl;
    __syncthreads();
    int wbase = 0;
    for (int w = 0; w < wv; ++w) wbase += ws[w];

    int ebase = bsum[blockIdx.x] + wbase + (incl - s);
    int o0 = ebase, o1 = o0 + a, o2 = o1 + b, o3 = o2 + c;
    if (base + 0 < N_NODES) { offsets[base + 0] = o0; cursor[base + 0] = o0; }
    if (base + 1 < N_NODES) { offsets[base + 1] = o1; cursor[base + 1] = o1; }
    if (base + 2 < N_NODES) { offsets[base + 2] = o2; cursor[base + 2] = o2; }
    if (base + 3 < N_NODES) { offsets[base + 3] = o3; cursor[base + 3] = o3; }
}

// ---------------------------------------------------------------------------
// CSR build step 3: fill edge records (src, a) bucketed by dst
// ---------------------------------------------------------------------------
__global__ void fill_kernel(const int* __restrict__ src,
                            const int* __restrict__ dst,
                            const float* __restrict__ a,
                            int* __restrict__ cursor,
                            int2* __restrict__ edges) {
    int e = blockIdx.x * blockDim.x + threadIdx.x;
    if (e < N_EDGES) {
        int pos = atomicAdd(&cursor[dst[e]], 1);
        edges[pos] = make_int2(src[e], __float_as_int(a[e]));
    }
}

// ---------------------------------------------------------------------------
// gather: hn[v][lane] = sum over edges (u->v) of a_e * h[u][lane]
// One wave per node; lane = feature column. Wave-uniform edge reads,
// 8-deep unroll into 4 accumulators for MLP.
// ---------------------------------------------------------------------------
__global__ __launch_bounds__(256) void gather_kernel(
        const float* __restrict__ h,
        const int2* __restrict__ edges,
        const int* __restrict__ offsets,
        float* __restrict__ hn) {
    const int lane = threadIdx.x & 63;
    const int node = (blockIdx.x * blockDim.x + threadIdx.x) >> 6;
    if (node >= N_NODES) return;

    const int beg = __builtin_amdgcn_readfirstlane(offsets[node]);
    const int end = __builtin_amdgcn_readfirstlane(offsets[node + 1]);

    float acc0 = 0.f, acc1 = 0.f, acc2 = 0.f, acc3 = 0.f;
    int i = beg;
    for (; i + 8 <= end; i += 8) {
        int2 e0 = edges[i + 0];
        int2 e1 = edges[i + 1];
        int2 e2 = edges[i + 2];
        int2 e3 = edges[i + 3];
        int2 e4 = edges[i + 4];
        int2 e5 = edges[i + 5];
        int2 e6 = edges[i + 6];
        int2 e7 = edges[i + 7];
        float h0 = h[(size_t)e0.x * DIM + lane];
        float h1 = h[(size_t)e1.x * DIM + lane];
        float h2 = h[(size_t)e2.x * DIM + lane];
        float h3 = h[(size_t)e3.x * DIM + lane];
        float h4 = h[(size_t)e4.x * DIM + lane];
        float h5 = h[(size_t)e5.x * DIM + lane];
        float h6 = h[(size_t)e6.x * DIM + lane];
        float h7 = h[(size_t)e7.x * DIM + lane];
        acc0 = fmaf(__int_as_float(e0.y), h0, acc0);
        acc1 = fmaf(__int_as_float(e1.y), h1, acc1);
        acc2 = fmaf(__int_as_float(e2.y), h2, acc2);
        acc3 = fmaf(__int_as_float(e3.y), h3, acc3);
        acc0 = fmaf(__int_as_float(e4.y), h4, acc0);
        acc1 = fmaf(__int_as_float(e5.y), h5, acc1);
        acc2 = fmaf(__int_as_float(e6.y), h6, acc2);
        acc3 = fmaf(__int_as_float(e7.y), h7, acc3);
    }
    for (; i < end; ++i) {
        int2 e = edges[i];
        acc0 = fmaf(__int_as_float(e.y), h[(size_t)e.x * DIM + lane], acc0);
    }
    hn[(size_t)node * DIM + lane] = (acc0 + acc1) + (acc2 + acc3);
}

// ---------------------------------------------------------------------------
// update: t1 = h + h_n ; t2 = h * h_n
//         h <- leaky(t1 @ W1 + b1) + leaky(t2 @ W2 + b2) ; also write to out
// ---------------------------------------------------------------------------
__global__ __launch_bounds__(256) void update_kernel(
        float* __restrict__ h,
        const float* __restrict__ hn,
        const float* __restrict__ W1,
        const float* __restrict__ b1,
        const float* __restrict__ W2,
        const float* __restrict__ b2,
        float* __restrict__ out,
        int out_col_base) {
    __shared__ float s_t1[4][DIM];
    __shared__ float s_t2[4][DIM];

    const int col  = threadIdx.x & 63;
    const int slot = threadIdx.x >> 6;

    float w1c[DIM], w2c[DIM];
#pragma unroll
    for (int k = 0; k < DIM; ++k) {
        w1c[k] = W1[k * DIM + col];
        w2c[k] = W2[k * DIM + col];
    }
    const float bb1 = b1[col];
    const float bb2 = b2[col];

    for (int base = blockIdx.x * 4; base < N_NODES; base += gridDim.x * 4) {
        const int node = base + slot;
        const bool valid = (node < N_NODES);
        float hv = 0.f, hnv = 0.f;
        if (valid) {
            hv  = h[node * DIM + col];
            hnv = hn[node * DIM + col];
        }
        s_t1[slot][col] = hv + hnv;
        s_t2[slot][col] = hv * hnv;
        __syncthreads();

        float acc1 = bb1, acc2 = bb2;
        const float4* t1v = (const float4*)s_t1[slot];
        const float4* t2v = (const float4*)s_t2[slot];
#pragma unroll
        for (int k0 = 0; k0 < DIM / 4; ++k0) {
            float4 t1 = t1v[k0];
            float4 t2 = t2v[k0];
            acc1 = fmaf(t1.x, w1c[4 * k0 + 0], acc1);
            acc1 = fmaf(t1.y, w1c[4 * k0 + 1], acc1);
            acc1 = fmaf(t1.z, w1c[4 * k0 + 2], acc1);
            acc1 = fmaf(t1.w, w1c[4 * k0 + 3], acc1);
            acc2 = fmaf(t2.x, w2c[4 * k0 + 0], acc2);
            acc2 = fmaf(t2.y, w2c[4 * k0 + 1], acc2);
            acc2 = fmaf(t2.z, w2c[4 * k0 + 2], acc2);
            acc2 = fmaf(t2.w, w2c[4 * k0 + 3], acc2);
        }
        __syncthreads();

        if (valid) {
            float r1 = acc1 > 0.f ? acc1 : 0.01f * acc1;
            float r2 = acc2 > 0.f ? acc2 : 0.01f * acc2;
            float hnew = r1 + r2;
            h[node * DIM + col] = hnew;
            out[node * OUT_COLS + out_col_base + col] = hnew;
        }
    }
}

// ---------------------------------------------------------------------------
extern "C" void kernel_launch(void* const* d_in, const int* in_sizes, int n_in,
                              void* d_out, int out_size, void* d_ws, size_t ws_size,
                              hipStream_t stream) {
    const float* x   = (const float*)d_in[0];
    const float* a   = (const float*)d_in[1];
    const float* W1s = (const float*)d_in[2];
    const float* b1s = (const float*)d_in[3];
    const float* W2s = (const float*)d_in[4];
    const float* b2s = (const float*)d_in[5];
    const int*   src = (const int*)d_in[6];
    const int*   dst = (const int*)d_in[7];
    float* out = (float*)d_out;

    // workspace layout
    float* h  = (float*)d_ws;                          // [N, 64]
    float* hn = h + (size_t)N_NODES * DIM;             // [N, 64]
    int* counts  = (int*)(hn + (size_t)N_NODES * DIM); // [N]
    int* offsets = counts + N_NODES;                   // [N+1]
    int* cursor  = offsets + N_NODES + 1;              // [N]
    int* bsum    = cursor + N_NODES;                   // [NBLK]
    uintptr_t p = (uintptr_t)(bsum + NBLK);
    p = (p + 15) & ~(uintptr_t)15;
    int2* edges = (int2*)p;                            // [E]

    // h = x ; out[:, :64] = x
    {
        int total = N_NODES * DIM / 4;
        init_kernel<<<(total + 255) / 256, 256, 0, stream>>>(x, h, out);
    }

    // build CSR (dst-bucketed edge list), once per launch
    hipMemsetAsync(counts, 0, N_NODES * sizeof(int), stream);
    hist_kernel<<<(N_EDGES / 4 + 255) / 256, 256, 0, stream>>>(dst, counts);
    blocksum_kernel<<<NBLK, 256, 0, stream>>>(counts, bsum);
    scanbsum_kernel<<<1, 128, 0, stream>>>(bsum, offsets);
    blockscan_kernel<<<NBLK, 256, 0, stream>>>(counts, bsum, offsets, cursor);
    fill_kernel<<<(N_EDGES + 255) / 256, 256, 0, stream>>>(src, dst, a, cursor, edges);

    for (int l = 0; l < 3; ++l) {
        gather_kernel<<<(N_NODES * 64 + 255) / 256, 256, 0, stream>>>(h, edges, offsets, hn);
        update_kernel<<<1024, 256, 0, stream>>>(
            h, hn,
            W1s + (size_t)l * DIM * DIM, b1s + (size_t)l * DIM,
            W2s + (size_t)l * DIM * DIM, b2s + (size_t)l * DIM,
            out, (l + 1) * DIM);
    }
}

// Round 4
// 955.822 us; speedup vs baseline: 9.0051x; 1.2610x over previous
//
#include <hip/hip_runtime.h>
#include <hip/hip_bf16.h>

#define N_NODES 100000
#define N_EDGES 3200000
#define DIM 64
#define OUT_COLS 256
#define ELEMS_PER_BLOCK 1024
#define NBLK ((N_NODES + ELEMS_PER_BLOCK - 1) / ELEMS_PER_BLOCK)   // 98

__device__ __forceinline__ unsigned short f2bf(float f) {
    __hip_bfloat16 b = __float2bfloat16(f);
    unsigned short u;
    __builtin_memcpy(&u, &b, 2);
    return u;
}
__device__ __forceinline__ float bflo(unsigned int p) { return __uint_as_float(p << 16); }
__device__ __forceinline__ float bfhi(unsigned int p) { return __uint_as_float(p & 0xFFFF0000u); }

// ---------------------------------------------------------------------------
// init: h = x ; h_bf = bf16(x) ; out[:, 0:64] = x
// ---------------------------------------------------------------------------
__global__ void init_kernel(const float* __restrict__ x,
                            float* __restrict__ h,
                            unsigned short* __restrict__ h_bf,
                            float* __restrict__ out) {
    int i = blockIdx.x * blockDim.x + threadIdx.x;   // float4 index
    const int total = N_NODES * DIM / 4;
    if (i < total) {
        float4 v = ((const float4*)x)[i];
        ((float4*)h)[i] = v;
        int elem = i * 4;
        int node = elem >> 6;
        int c    = elem & 63;
        *(float4*)&out[node * OUT_COLS + c] = v;
        unsigned int lo = (unsigned int)f2bf(v.x) | ((unsigned int)f2bf(v.y) << 16);
        unsigned int hi = (unsigned int)f2bf(v.z) | ((unsigned int)f2bf(v.w) << 16);
        *(uint2*)&h_bf[elem] = make_uint2(lo, hi);
    }
}

// ---------------------------------------------------------------------------
// CSR build step 1: histogram of dst (4 edges / thread)
// ---------------------------------------------------------------------------
__global__ void hist_kernel(const int* __restrict__ dst, int* __restrict__ counts) {
    int t = blockIdx.x * blockDim.x + threadIdx.x;
    int e = t * 4;
    if (e + 4 <= N_EDGES) {
        int4 d = *(const int4*)&dst[e];
        atomicAdd(&counts[d.x], 1);
        atomicAdd(&counts[d.y], 1);
        atomicAdd(&counts[d.z], 1);
        atomicAdd(&counts[d.w], 1);
    } else {
        for (int k = e; k < N_EDGES; ++k) atomicAdd(&counts[dst[k]], 1);
    }
}

// ---------------------------------------------------------------------------
// scan A: per-block sums of counts (1024 elems / block)
// ---------------------------------------------------------------------------
__global__ __launch_bounds__(256) void blocksum_kernel(const int* __restrict__ counts,
                                                       int* __restrict__ bsum) {
    const int t = threadIdx.x;
    const int base = blockIdx.x * ELEMS_PER_BLOCK + t * 4;
    int s = 0;
#pragma unroll
    for (int k = 0; k < 4; ++k) {
        int idx = base + k;
        if (idx < N_NODES) s += counts[idx];
    }
    for (int off = 32; off > 0; off >>= 1) s += __shfl_down(s, off);
    __shared__ int ws[4];
    const int lane = t & 63, wv = t >> 6;
    if (lane == 0) ws[wv] = s;
    __syncthreads();
    if (t == 0) bsum[blockIdx.x] = ws[0] + ws[1] + ws[2] + ws[3];
}

// ---------------------------------------------------------------------------
// scan B: exclusive-scan the 98 block sums (single small block)
// ---------------------------------------------------------------------------
__global__ __launch_bounds__(128) void scanbsum_kernel(int* __restrict__ bsum,
                                                       int* __restrict__ offsets) {
    __shared__ int s[128];
    const int t = threadIdx.x;
    int v = (t < NBLK) ? bsum[t] : 0;
    s[t] = v;
    __syncthreads();
    for (int off = 1; off < 128; off <<= 1) {
        int u = (t >= off) ? s[t - off] : 0;
        __syncthreads();
        s[t] += u;
        __syncthreads();
    }
    if (t < NBLK) bsum[t] = s[t] - v;          // exclusive
    if (t == 127) offsets[N_NODES] = s[127];   // total edge count
}

// ---------------------------------------------------------------------------
// scan C: block-local exclusive scan + write offsets & cursor
// ---------------------------------------------------------------------------
__global__ __launch_bounds__(256) void blockscan_kernel(const int* __restrict__ counts,
                                                        const int* __restrict__ bsum,
                                                        int* __restrict__ offsets,
                                                        int* __restrict__ cursor) {
    const int t = threadIdx.x;
    const int base = blockIdx.x * ELEMS_PER_BLOCK + t * 4;
    int a = 0, b = 0, c = 0, d = 0;
    if (base + 0 < N_NODES) a = counts[base + 0];
    if (base + 1 < N_NODES) b = counts[base + 1];
    if (base + 2 < N_NODES) c = counts[base + 2];
    if (base + 3 < N_NODES) d = counts[base + 3];
    const int s = a + b + c + d;

    int incl = s;
    const int lane = t & 63, wv = t >> 6;
    for (int off = 1; off < 64; off <<= 1) {
        int u = __shfl_up(incl, off);
        if (lane >= off) incl += u;
    }
    __shared__ int ws[4];
    if (lane == 63) ws[wv] = incl;
    __syncthreads();
    int wbase = 0;
    for (int w = 0; w < wv; ++w) wbase += ws[w];

    int ebase = bsum[blockIdx.x] + wbase + (incl - s);
    int o0 = ebase, o1 = o0 + a, o2 = o1 + b, o3 = o2 + c;
    if (base + 0 < N_NODES) { offsets[base + 0] = o0; cursor[base + 0] = o0; }
    if (base + 1 < N_NODES) { offsets[base + 1] = o1; cursor[base + 1] = o1; }
    if (base + 2 < N_NODES) { offsets[base + 2] = o2; cursor[base + 2] = o2; }
    if (base + 3 < N_NODES) { offsets[base + 3] = o3; cursor[base + 3] = o3; }
}

// ---------------------------------------------------------------------------
// CSR build step 3: fill edge records (src, a) bucketed by dst
// ---------------------------------------------------------------------------
__global__ void fill_kernel(const int* __restrict__ src,
                            const int* __restrict__ dst,
                            const float* __restrict__ a,
                            int* __restrict__ cursor,
                            long long* __restrict__ edges) {
    int e = blockIdx.x * blockDim.x + threadIdx.x;
    if (e < N_EDGES) {
        int pos = atomicAdd(&cursor[dst[e]], 1);
        // record: low 32 = src, high 32 = a  (matches int2 {x=src, y=a})
        long long rec = (long long)((unsigned long long)(unsigned int)__float_as_int(a[e]) << 32)
                      | (unsigned int)src[e];
        __builtin_nontemporal_store(rec, &edges[pos]);
    }
}

// ---------------------------------------------------------------------------
// gather: hn[v][:] = sum over edges (u->v) of a_e * h_bf[u][:]
// Half-wave (32 lanes) per node; lane covers 2 feature cols via bf16x2 load.
// fp32 accumulation, 4-deep unroll, no atomics.
// ---------------------------------------------------------------------------
__global__ __launch_bounds__(256) void gather_kernel(
        const unsigned short* __restrict__ h_bf,
        const int2* __restrict__ edges,
        const int* __restrict__ offsets,
        float* __restrict__ hn) {
    const int lane   = threadIdx.x & 63;
    const int half   = lane >> 5;            // which node within the wave
    const int sub    = lane & 31;            // column-pair index
    const int waveid = (blockIdx.x * blockDim.x + threadIdx.x) >> 6;
    const int node   = waveid * 2 + half;
    if (node >= N_NODES) return;

    const int beg = offsets[node];
    const int end = offsets[node + 1];
    const int col2 = sub * 2;

    float al0 = 0.f, al1 = 0.f, al2 = 0.f, al3 = 0.f;   // low cols
    float ah0 = 0.f, ah1 = 0.f, ah2 = 0.f, ah3 = 0.f;   // high cols
    int i = beg;
    for (; i + 4 <= end; i += 4) {
        int2 e0 = edges[i + 0];
        int2 e1 = edges[i + 1];
        int2 e2 = edges[i + 2];
        int2 e3 = edges[i + 3];
        unsigned int p0 = *(const unsigned int*)&h_bf[(size_t)e0.x * DIM + col2];
        unsigned int p1 = *(const unsigned int*)&h_bf[(size_t)e1.x * DIM + col2];
        unsigned int p2 = *(const unsigned int*)&h_bf[(size_t)e2.x * DIM + col2];
        unsigned int p3 = *(const unsigned int*)&h_bf[(size_t)e3.x * DIM + col2];
        float w0 = __int_as_float(e0.y);
        float w1 = __int_as_float(e1.y);
        float w2 = __int_as_float(e2.y);
        float w3 = __int_as_float(e3.y);
        al0 = fmaf(w0, bflo(p0), al0);  ah0 = fmaf(w0, bfhi(p0), ah0);
        al1 = fmaf(w1, bflo(p1), al1);  ah1 = fmaf(w1, bfhi(p1), ah1);
        al2 = fmaf(w2, bflo(p2), al2);  ah2 = fmaf(w2, bfhi(p2), ah2);
        al3 = fmaf(w3, bflo(p3), al3);  ah3 = fmaf(w3, bfhi(p3), ah3);
    }
    for (; i < end; ++i) {
        int2 e = edges[i];
        unsigned int p = *(const unsigned int*)&h_bf[(size_t)e.x * DIM + col2];
        float w = __int_as_float(e.y);
        al0 = fmaf(w, bflo(p), al0);
        ah0 = fmaf(w, bfhi(p), ah0);
    }
    float lo = (al0 + al1) + (al2 + al3);
    float hi = (ah0 + ah1) + (ah2 + ah3);
    *(float2*)&hn[(size_t)node * DIM + col2] = make_float2(lo, hi);
}

// ---------------------------------------------------------------------------
// update: t1 = h + h_n ; t2 = h * h_n
//         h <- leaky(t1 @ W1 + b1) + leaky(t2 @ W2 + b2)
//         writes h (fp32), h_bf (bf16 shadow), out column block.
// Double-buffered LDS: one barrier per node-group.
// ---------------------------------------------------------------------------
__global__ __launch_bounds__(256) void update_kernel(
        float* __restrict__ h,
        unsigned short* __restrict__ h_bf,
        const float* __restrict__ hn,
        const float* __restrict__ W1,
        const float* __restrict__ b1,
        const float* __restrict__ W2,
        const float* __restrict__ b2,
        float* __restrict__ out,
        int out_col_base) {
    __shared__ float s_t1[2][4][DIM];
    __shared__ float s_t2[2][4][DIM];

    const int col  = threadIdx.x & 63;
    const int slot = threadIdx.x >> 6;

    float w1c[DIM], w2c[DIM];
#pragma unroll
    for (int k = 0; k < DIM; ++k) {
        w1c[k] = W1[k * DIM + col];
        w2c[k] = W2[k * DIM + col];
    }
    const float bb1 = b1[col];
    const float bb2 = b2[col];

    int buf = 0;
    for (int base = blockIdx.x * 4; base < N_NODES; base += gridDim.x * 4, buf ^= 1) {
        const int node = base + slot;
        const bool valid = (node < N_NODES);
        float hv = 0.f, hnv = 0.f;
        if (valid) {
            hv  = h[node * DIM + col];
            hnv = hn[node * DIM + col];
        }
        s_t1[buf][slot][col] = hv + hnv;
        s_t2[buf][slot][col] = hv * hnv;
        __syncthreads();

        float acc1 = bb1, acc2 = bb2;
        const float4* t1v = (const float4*)s_t1[buf][slot];
        const float4* t2v = (const float4*)s_t2[buf][slot];
#pragma unroll
        for (int k0 = 0; k0 < DIM / 4; ++k0) {
            float4 t1 = t1v[k0];
            float4 t2 = t2v[k0];
            acc1 = fmaf(t1.x, w1c[4 * k0 + 0], acc1);
            acc1 = fmaf(t1.y, w1c[4 * k0 + 1], acc1);
            acc1 = fmaf(t1.z, w1c[4 * k0 + 2], acc1);
            acc1 = fmaf(t1.w, w1c[4 * k0 + 3], acc1);
            acc2 = fmaf(t2.x, w2c[4 * k0 + 0], acc2);
            acc2 = fmaf(t2.y, w2c[4 * k0 + 1], acc2);
            acc2 = fmaf(t2.z, w2c[4 * k0 + 2], acc2);
            acc2 = fmaf(t2.w, w2c[4 * k0 + 3], acc2);
        }

        if (valid) {
            float r1 = acc1 > 0.f ? acc1 : 0.01f * acc1;
            float r2 = acc2 > 0.f ? acc2 : 0.01f * acc2;
            float hnew = r1 + r2;
            h[node * DIM + col] = hnew;
            h_bf[node * DIM + col] = f2bf(hnew);
            out[node * OUT_COLS + out_col_base + col] = hnew;
        }
    }
}

// ---------------------------------------------------------------------------
extern "C" void kernel_launch(void* const* d_in, const int* in_sizes, int n_in,
                              void* d_out, int out_size, void* d_ws, size_t ws_size,
                              hipStream_t stream) {
    const float* x   = (const float*)d_in[0];
    const float* a   = (const float*)d_in[1];
    const float* W1s = (const float*)d_in[2];
    const float* b1s = (const float*)d_in[3];
    const float* W2s = (const float*)d_in[4];
    const float* b2s = (const float*)d_in[5];
    const int*   src = (const int*)d_in[6];
    const int*   dst = (const int*)d_in[7];
    float* out = (float*)d_out;

    // workspace layout
    float* h  = (float*)d_ws;                            // [N, 64] fp32
    float* hn = h + (size_t)N_NODES * DIM;               // [N, 64] fp32
    unsigned short* h_bf = (unsigned short*)(hn + (size_t)N_NODES * DIM); // [N,64] bf16
    int* counts  = (int*)(h_bf + (size_t)N_NODES * DIM); // [N]
    int* offsets = counts + N_NODES;                     // [N+1]
    int* cursor  = offsets + N_NODES + 1;                // [N]
    int* bsum    = cursor + N_NODES;                     // [NBLK]
    uintptr_t p = (uintptr_t)(bsum + NBLK);
    p = (p + 15) & ~(uintptr_t)15;
    int2* edges = (int2*)p;                              // [E]

    // h = x ; h_bf = bf16(x) ; out[:, :64] = x
    {
        int total = N_NODES * DIM / 4;
        init_kernel<<<(total + 255) / 256, 256, 0, stream>>>(x, h, h_bf, out);
    }

    // build CSR (dst-bucketed edge list), once per launch
    hipMemsetAsync(counts, 0, N_NODES * sizeof(int), stream);
    hist_kernel<<<(N_EDGES / 4 + 255) / 256, 256, 0, stream>>>(dst, counts);
    blocksum_kernel<<<NBLK, 256, 0, stream>>>(counts, bsum);
    scanbsum_kernel<<<1, 128, 0, stream>>>(bsum, offsets);
    blockscan_kernel<<<NBLK, 256, 0, stream>>>(counts, bsum, offsets, cursor);
    fill_kernel<<<(N_EDGES + 255) / 256, 256, 0, stream>>>(src, dst, a, cursor, (long long*)edges);

    for (int l = 0; l < 3; ++l) {
        // half-wave per node: 2 nodes per wave, 8 nodes per 256-thread block
        int waves = (N_NODES + 1) / 2;
        int blocks = (waves * 64 + 255) / 256;
        gather_kernel<<<blocks, 256, 0, stream>>>(h_bf, edges, offsets, hn);
        update_kernel<<<2048, 256, 0, stream>>>(
            h, h_bf, hn,
            W1s + (size_t)l * DIM * DIM, b1s + (size_t)l * DIM,
            W2s + (size_t)l * DIM * DIM, b2s + (size_t)l * DIM,
            out, (l + 1) * DIM);
    }
}

// Round 5
// 722.769 us; speedup vs baseline: 11.9087x; 1.3224x over previous
//
#include <hip/hip_runtime.h>
#include <hip/hip_bf16.h>

#define N_NODES 100000
#define N_EDGES 3200000
#define DIM 64
#define OUT_COLS 256
#define BUCKET_SHIFT 8                                   // 256 nodes per bucket
#define NBUCK ((N_NODES + 255) / 256)                    // 391
#define TILE 4096                                        // edges per binning block
#define NTILEBLK ((N_EDGES + TILE - 1) / TILE)           // 782

__device__ __forceinline__ unsigned short f2bf(float f) {
    __hip_bfloat16 b = __float2bfloat16(f);
    unsigned short u;
    __builtin_memcpy(&u, &b, 2);
    return u;
}
__device__ __forceinline__ float bflo(unsigned int p) { return __uint_as_float(p << 16); }
__device__ __forceinline__ float bfhi(unsigned int p) { return __uint_as_float(p & 0xFFFF0000u); }

// ---------------------------------------------------------------------------
// init: h = x ; h_bf = bf16(x) ; out[:, 0:64] = x
// ---------------------------------------------------------------------------
__global__ void init_kernel(const float* __restrict__ x,
                            float* __restrict__ h,
                            unsigned short* __restrict__ h_bf,
                            float* __restrict__ out) {
    int i = blockIdx.x * blockDim.x + threadIdx.x;   // float4 index
    const int total = N_NODES * DIM / 4;
    if (i < total) {
        float4 v = ((const float4*)x)[i];
        ((float4*)h)[i] = v;
        int elem = i * 4;
        int node = elem >> 6;
        int c    = elem & 63;
        *(float4*)&out[node * OUT_COLS + c] = v;
        unsigned int lo = (unsigned int)f2bf(v.x) | ((unsigned int)f2bf(v.y) << 16);
        unsigned int hi = (unsigned int)f2bf(v.z) | ((unsigned int)f2bf(v.w) << 16);
        *(uint2*)&h_bf[elem] = make_uint2(lo, hi);
    }
}

// ---------------------------------------------------------------------------
// bucket_hist: per-bucket edge counts (LDS-binned, 1 global atomic per
// (block,bucket) instead of per edge)
// ---------------------------------------------------------------------------
__global__ __launch_bounds__(256) void bucket_hist_kernel(const int* __restrict__ dst,
                                                          int* __restrict__ bucket_count) {
    __shared__ int lc[NBUCK];
    for (int b = threadIdx.x; b < NBUCK; b += 256) lc[b] = 0;
    __syncthreads();
    const int base = blockIdx.x * TILE;
#pragma unroll
    for (int k = 0; k < TILE / 256; ++k) {
        int e = base + k * 256 + threadIdx.x;
        if (e < N_EDGES) atomicAdd(&lc[((unsigned)dst[e]) >> BUCKET_SHIFT], 1);
    }
    __syncthreads();
    for (int b = threadIdx.x; b < NBUCK; b += 256) {
        int c = lc[b];
        if (c) atomicAdd(&bucket_count[b], c);
    }
}

// ---------------------------------------------------------------------------
// bucket_scan: exclusive scan of 391 bucket counts -> base & cursor
// ---------------------------------------------------------------------------
__global__ __launch_bounds__(512) void bucket_scan_kernel(const int* __restrict__ bucket_count,
                                                          int* __restrict__ bucket_base,
                                                          int* __restrict__ bucket_cursor,
                                                          int* __restrict__ offsets) {
    __shared__ int s[512];
    const int t = threadIdx.x;
    int v = (t < NBUCK) ? bucket_count[t] : 0;
    s[t] = v;
    __syncthreads();
    for (int off = 1; off < 512; off <<= 1) {
        int u = (t >= off) ? s[t - off] : 0;
        __syncthreads();
        s[t] += u;
        __syncthreads();
    }
    if (t < NBUCK) { int b = s[t] - v; bucket_base[t] = b; bucket_cursor[t] = b; }
    if (t == 0) offsets[N_NODES] = N_EDGES;
}

// ---------------------------------------------------------------------------
// binA: stage edges bucket-contiguously (per-block runs reserved with one
// global atomic per bucket). record = {src | dstlocal<<24, a}
// ---------------------------------------------------------------------------
__global__ __launch_bounds__(256) void binA_kernel(const int* __restrict__ src,
                                                   const int* __restrict__ dst,
                                                   const float* __restrict__ a,
                                                   int* __restrict__ bucket_cursor,
                                                   int2* __restrict__ temp) {
    __shared__ int lcount[NBUCK];
    __shared__ int lbase[NBUCK];
    for (int b = threadIdx.x; b < NBUCK; b += 256) lcount[b] = 0;
    __syncthreads();
    const int base = blockIdx.x * TILE;
    int dv[TILE / 256], rk[TILE / 256];
#pragma unroll
    for (int k = 0; k < TILE / 256; ++k) {
        int e = base + k * 256 + threadIdx.x;
        dv[k] = 0; rk[k] = 0;
        if (e < N_EDGES) {
            int d = dst[e];
            dv[k] = d;
            rk[k] = atomicAdd(&lcount[((unsigned)d) >> BUCKET_SHIFT], 1);
        }
    }
    __syncthreads();
    for (int b = threadIdx.x; b < NBUCK; b += 256) {
        int c = lcount[b];
        if (c) lbase[b] = atomicAdd(&bucket_cursor[b], c);
    }
    __syncthreads();
#pragma unroll
    for (int k = 0; k < TILE / 256; ++k) {
        int e = base + k * 256 + threadIdx.x;
        if (e < N_EDGES) {
            int d = dv[k];
            int pos = lbase[((unsigned)d) >> BUCKET_SHIFT] + rk[k];
            int packed = src[e] | ((d & 255) << 24);
            temp[pos] = make_int2(packed, __float_as_int(a[e]));
        }
    }
}

// ---------------------------------------------------------------------------
// binB: one block per bucket. Per-node counts + scan in LDS (produces
// offsets), then scatter to exact CSR slots via LDS cursors. All random
// writes stay in a ~64 KB window -> XCD-local L2, no HBM line bouncing.
// ---------------------------------------------------------------------------
__global__ __launch_bounds__(256) void binB_kernel(const int2* __restrict__ temp,
                                                   const int* __restrict__ bucket_base,
                                                   const int* __restrict__ bucket_count,
                                                   int* __restrict__ offsets,
                                                   int2* __restrict__ edges) {
    const int b = blockIdx.x;
    const int node0 = b << BUCKET_SHIFT;
    const int nodes = min(256, N_NODES - node0);
    const int beg = bucket_base[b];
    const int cnt = bucket_count[b];
    const int t = threadIdx.x;

    __shared__ int ncount[256];
    __shared__ int ssc[256];
    __shared__ int ncur[256];
    ncount[t] = 0;
    __syncthreads();
    for (int i = t; i < cnt; i += 256) {
        unsigned w0 = (unsigned)temp[beg + i].x;
        atomicAdd(&ncount[w0 >> 24], 1);
    }
    __syncthreads();
    int v = ncount[t];
    ssc[t] = v;
    __syncthreads();
    for (int off = 1; off < 256; off <<= 1) {
        int u = (t >= off) ? ssc[t - off] : 0;
        __syncthreads();
        ssc[t] += u;
        __syncthreads();
    }
    int excl = ssc[t] - v;
    if (t < nodes) offsets[node0 + t] = beg + excl;
    ncur[t] = beg + excl;
    __syncthreads();
    for (int i = t; i < cnt; i += 256) {
        int2 r = temp[beg + i];
        int loc = ((unsigned)r.x) >> 24;
        int pos = atomicAdd(&ncur[loc], 1);
        edges[pos] = make_int2(r.x & 0xFFFFFF, r.y);
    }
}

// ---------------------------------------------------------------------------
// gather: hn[v][:] = sum over edges (u->v) of a_e * h_bf[u][:]
// Half-wave (32 lanes) per node; lane covers 2 feature cols via bf16x2 load.
// ---------------------------------------------------------------------------
__global__ __launch_bounds__(256) void gather_kernel(
        const unsigned short* __restrict__ h_bf,
        const int2* __restrict__ edges,
        const int* __restrict__ offsets,
        float* __restrict__ hn) {
    const int lane   = threadIdx.x & 63;
    const int half   = lane >> 5;
    const int sub    = lane & 31;
    const int waveid = (blockIdx.x * blockDim.x + threadIdx.x) >> 6;
    const int node   = waveid * 2 + half;
    if (node >= N_NODES) return;

    const int beg = offsets[node];
    const int end = offsets[node + 1];
    const int col2 = sub * 2;

    float al0 = 0.f, al1 = 0.f, al2 = 0.f, al3 = 0.f;
    float ah0 = 0.f, ah1 = 0.f, ah2 = 0.f, ah3 = 0.f;
    int i = beg;
    for (; i + 4 <= end; i += 4) {
        int2 e0 = edges[i + 0];
        int2 e1 = edges[i + 1];
        int2 e2 = edges[i + 2];
        int2 e3 = edges[i + 3];
        unsigned int p0 = *(const unsigned int*)&h_bf[(size_t)e0.x * DIM + col2];
        unsigned int p1 = *(const unsigned int*)&h_bf[(size_t)e1.x * DIM + col2];
        unsigned int p2 = *(const unsigned int*)&h_bf[(size_t)e2.x * DIM + col2];
        unsigned int p3 = *(const unsigned int*)&h_bf[(size_t)e3.x * DIM + col2];
        float w0 = __int_as_float(e0.y);
        float w1 = __int_as_float(e1.y);
        float w2 = __int_as_float(e2.y);
        float w3 = __int_as_float(e3.y);
        al0 = fmaf(w0, bflo(p0), al0);  ah0 = fmaf(w0, bfhi(p0), ah0);
        al1 = fmaf(w1, bflo(p1), al1);  ah1 = fmaf(w1, bfhi(p1), ah1);
        al2 = fmaf(w2, bflo(p2), al2);  ah2 = fmaf(w2, bfhi(p2), ah2);
        al3 = fmaf(w3, bflo(p3), al3);  ah3 = fmaf(w3, bfhi(p3), ah3);
    }
    for (; i < end; ++i) {
        int2 e = edges[i];
        unsigned int p = *(const unsigned int*)&h_bf[(size_t)e.x * DIM + col2];
        float w = __int_as_float(e.y);
        al0 = fmaf(w, bflo(p), al0);
        ah0 = fmaf(w, bfhi(p), ah0);
    }
    float lo = (al0 + al1) + (al2 + al3);
    float hi = (ah0 + ah1) + (ah2 + ah3);
    *(float2*)&hn[(size_t)node * DIM + col2] = make_float2(lo, hi);
}

// ---------------------------------------------------------------------------
// update: t1 = h + h_n ; t2 = h * h_n
//         h <- leaky(t1 @ W1 + b1) + leaky(t2 @ W2 + b2)
// ---------------------------------------------------------------------------
__global__ __launch_bounds__(256) void update_kernel(
        float* __restrict__ h,
        unsigned short* __restrict__ h_bf,
        const float* __restrict__ hn,
        const float* __restrict__ W1,
        const float* __restrict__ b1,
        const float* __restrict__ W2,
        const float* __restrict__ b2,
        float* __restrict__ out,
        int out_col_base) {
    __shared__ float s_t1[2][4][DIM];
    __shared__ float s_t2[2][4][DIM];

    const int col  = threadIdx.x & 63;
    const int slot = threadIdx.x >> 6;

    float w1c[DIM], w2c[DIM];
#pragma unroll
    for (int k = 0; k < DIM; ++k) {
        w1c[k] = W1[k * DIM + col];
        w2c[k] = W2[k * DIM + col];
    }
    const float bb1 = b1[col];
    const float bb2 = b2[col];

    int buf = 0;
    for (int base = blockIdx.x * 4; base < N_NODES; base += gridDim.x * 4, buf ^= 1) {
        const int node = base + slot;
        const bool valid = (node < N_NODES);
        float hv = 0.f, hnv = 0.f;
        if (valid) {
            hv  = h[node * DIM + col];
            hnv = hn[node * DIM + col];
        }
        s_t1[buf][slot][col] = hv + hnv;
        s_t2[buf][slot][col] = hv * hnv;
        __syncthreads();

        float acc1 = bb1, acc2 = bb2;
        const float4* t1v = (const float4*)s_t1[buf][slot];
        const float4* t2v = (const float4*)s_t2[buf][slot];
#pragma unroll
        for (int k0 = 0; k0 < DIM / 4; ++k0) {
            float4 t1 = t1v[k0];
            float4 t2 = t2v[k0];
            acc1 = fmaf(t1.x, w1c[4 * k0 + 0], acc1);
            acc1 = fmaf(t1.y, w1c[4 * k0 + 1], acc1);
            acc1 = fmaf(t1.z, w1c[4 * k0 + 2], acc1);
            acc1 = fmaf(t1.w, w1c[4 * k0 + 3], acc1);
            acc2 = fmaf(t2.x, w2c[4 * k0 + 0], acc2);
            acc2 = fmaf(t2.y, w2c[4 * k0 + 1], acc2);
            acc2 = fmaf(t2.z, w2c[4 * k0 + 2], acc2);
            acc2 = fmaf(t2.w, w2c[4 * k0 + 3], acc2);
        }

        if (valid) {
            float r1 = acc1 > 0.f ? acc1 : 0.01f * acc1;
            float r2 = acc2 > 0.f ? acc2 : 0.01f * acc2;
            float hnew = r1 + r2;
            h[node * DIM + col] = hnew;
            h_bf[node * DIM + col] = f2bf(hnew);
            out[node * OUT_COLS + out_col_base + col] = hnew;
        }
    }
}

// ---------------------------------------------------------------------------
extern "C" void kernel_launch(void* const* d_in, const int* in_sizes, int n_in,
                              void* d_out, int out_size, void* d_ws, size_t ws_size,
                              hipStream_t stream) {
    const float* x   = (const float*)d_in[0];
    const float* a   = (const float*)d_in[1];
    const float* W1s = (const float*)d_in[2];
    const float* b1s = (const float*)d_in[3];
    const float* W2s = (const float*)d_in[4];
    const float* b2s = (const float*)d_in[5];
    const int*   src = (const int*)d_in[6];
    const int*   dst = (const int*)d_in[7];
    float* out = (float*)d_out;

    // workspace layout
    float* h  = (float*)d_ws;                              // [N, 64] fp32
    float* hn = h + (size_t)N_NODES * DIM;                 // [N, 64] fp32 (doubles as binA staging: 3.2M int2 = 25.6 MB exactly)
    unsigned short* h_bf = (unsigned short*)(hn + (size_t)N_NODES * DIM); // [N,64] bf16
    int* offsets       = (int*)(h_bf + (size_t)N_NODES * DIM);  // [N+1]
    int* bucket_count  = offsets + N_NODES + 1;            // [NBUCK]
    int* bucket_base   = bucket_count + NBUCK;             // [NBUCK]
    int* bucket_cursor = bucket_base + NBUCK;              // [NBUCK]
    uintptr_t p = (uintptr_t)(bucket_cursor + NBUCK);
    p = (p + 15) & ~(uintptr_t)15;
    int2* edges = (int2*)p;                                // [E]
    int2* temp  = (int2*)hn;                               // binA staging

    // h = x ; h_bf = bf16(x) ; out[:, :64] = x
    {
        int total = N_NODES * DIM / 4;
        init_kernel<<<(total + 255) / 256, 256, 0, stream>>>(x, h, h_bf, out);
    }

    // CSR build: bucket-hist -> tiny scan -> bin (coalesced runs) -> place (L2-local)
    hipMemsetAsync(bucket_count, 0, NBUCK * sizeof(int), stream);
    bucket_hist_kernel<<<NTILEBLK, 256, 0, stream>>>(dst, bucket_count);
    bucket_scan_kernel<<<1, 512, 0, stream>>>(bucket_count, bucket_base, bucket_cursor, offsets);
    binA_kernel<<<NTILEBLK, 256, 0, stream>>>(src, dst, a, bucket_cursor, temp);
    binB_kernel<<<NBUCK, 256, 0, stream>>>(temp, bucket_base, bucket_count, offsets, edges);

    for (int l = 0; l < 3; ++l) {
        int waves = (N_NODES + 1) / 2;
        int blocks = (waves * 64 + 255) / 256;
        gather_kernel<<<blocks, 256, 0, stream>>>(h_bf, edges, offsets, hn);
        update_kernel<<<2048, 256, 0, stream>>>(
            h, h_bf, hn,
            W1s + (size_t)l * DIM * DIM, b1s + (size_t)l * DIM,
            W2s + (size_t)l * DIM * DIM, b2s + (size_t)l * DIM,
            out, (l + 1) * DIM);
    }
}